// Round 11
// baseline (167.445 us; speedup 1.0000x reference)
//
#include <hip/hip_runtime.h>
#include <hip/hip_bf16.h>

typedef __attribute__((ext_vector_type(8))) short bf16x8;
typedef __attribute__((ext_vector_type(4))) float f32x4;
typedef __attribute__((ext_vector_type(16))) float f32x16;
typedef __attribute__((ext_vector_type(4))) ushort u16x4;

#define AS1 __attribute__((address_space(1)))
#define AS3 __attribute__((address_space(3)))

static __device__ __forceinline__ ushort f2b(float f) {
    union { float f; unsigned u; } v;
    v.f = f;
    unsigned r = v.u + 0x7FFF + ((v.u >> 16) & 1);
    return (ushort)(r >> 16);
}

// ---------------- fused f32 -> bf16 conversion (x, Wq, Wkv, Wo) ----------------
__global__ __launch_bounds__(256) void cvt_all(const float* __restrict__ x,
                                               const float* __restrict__ Wq,
                                               const float* __restrict__ Wkv,
                                               const float* __restrict__ Wo,
                                               ushort* __restrict__ xb,
                                               ushort* __restrict__ wqkvb,
                                               ushort* __restrict__ wob)
{
    int i = blockIdx.x * blockDim.x + threadIdx.x;
    const int stride = gridDim.x * blockDim.x;
    for (; i < 4325376; i += stride) {
        const float4* src; ushort4* dst; int j;
        if (i < 2097152)      { src = (const float4*)x;   dst = (ushort4*)xb;              j = i; }
        else if (i < 3145728) { src = (const float4*)Wq;  dst = (ushort4*)wqkvb;           j = i - 2097152; }
        else if (i < 3276800) { src = (const float4*)Wkv; dst = (ushort4*)wqkvb + 1048576; j = i - 3145728; }
        else                  { src = (const float4*)Wo;  dst = (ushort4*)wob;             j = i - 3276800; }
        float4 v = src[j];
        ushort4 o; o.x = f2b(v.x); o.y = f2b(v.y); o.z = f2b(v.z); o.w = f2b(v.w);
        dst[j] = o;
    }
}

// ---------------- bf16 GEMM: C = A * B^T (r10 best: BK=64 dbuf + 8 waves) -------------
// 128x128 tile, BK=64, 8 waves (2M x 4N), per-wave 64x32 (4x2 frags, 16 MFMA/K-step).
// 64 KiB LDS, 512 blocks = exactly 2.0 blocks/CU. Measured 48.5 us (708 TF).
template<bool F32OUT>
__global__ __launch_bounds__(512) void gemm_bt(const ushort* __restrict__ A,
                                               const ushort* __restrict__ B,
                                               void* __restrict__ Cv,
                                               int M, int N, int K)
{
    __shared__ ushort As[2][128 * 64];
    __shared__ ushort Bs[2][128 * 64];
    const int tid  = threadIdx.x;
    const int lane = tid & 63;
    const int wid  = tid >> 6;
    const int l15  = lane & 15;
    const int lg   = lane >> 4;
    const int nwg8 = gridDim.x >> 3;
    const int kblk = blockIdx.x;
    const int swz  = (kblk & 7) * nwg8 + (kblk >> 3);
    const int nx   = N >> 7;
    const int brow = (swz / nx) * 128;
    const int bcol = (swz % nx) * 128;
    const int wr = wid >> 2, wc = wid & 3;

    f32x4 acc[4][2] = {};

    auto stage = [&](int bi, int k0) {
        const ushort* Ap = A + (size_t)brow * K + k0;
        const ushort* Bp = B + (size_t)bcol * K + k0;
#pragma unroll
        for (int j = 0; j < 2; ++j) {
            const int G = j * 512 + tid;
            const int r = G >> 3;
            const int s = (G & 7) ^ (r & 7);
            const int dc = j * 4096 + (wid << 9);
            __builtin_amdgcn_global_load_lds(
                (const AS1 void*)(Ap + (size_t)r * K + s * 8),
                (AS3 void*)(&As[bi][dc]), 16, 0, 0);
            __builtin_amdgcn_global_load_lds(
                (const AS1 void*)(Bp + (size_t)r * K + s * 8),
                (AS3 void*)(&Bs[bi][dc]), 16, 0, 0);
        }
    };

    stage(0, 0);
    __syncthreads();
    int cur = 0;

    for (int k0 = 0; k0 < K; k0 += 64) {
        if (k0 + 64 < K) stage(cur ^ 1, k0 + 64);

        bf16x8 af[4][2], bfr[2][2];
#pragma unroll
        for (int m = 0; m < 4; ++m) {
            int row = wr * 64 + m * 16 + l15;
#pragma unroll
            for (int kh = 0; kh < 2; ++kh) {
                int sl = (kh * 4 + lg) ^ (row & 7);
                af[m][kh] = *(const bf16x8*)(&As[cur][row * 64 + sl * 8]);
            }
        }
#pragma unroll
        for (int n = 0; n < 2; ++n) {
            int row = wc * 32 + n * 16 + l15;
#pragma unroll
            for (int kh = 0; kh < 2; ++kh) {
                int sl = (kh * 4 + lg) ^ (row & 7);
                bfr[n][kh] = *(const bf16x8*)(&Bs[cur][row * 64 + sl * 8]);
            }
        }
#pragma unroll
        for (int m = 0; m < 4; ++m)
#pragma unroll
            for (int n = 0; n < 2; ++n) {
                acc[m][n] = __builtin_amdgcn_mfma_f32_16x16x32_bf16(af[m][0], bfr[n][0], acc[m][n], 0, 0, 0);
                acc[m][n] = __builtin_amdgcn_mfma_f32_16x16x32_bf16(af[m][1], bfr[n][1], acc[m][n], 0, 0, 0);
            }

        __syncthreads();
        cur ^= 1;
    }

#pragma unroll
    for (int m = 0; m < 4; ++m)
#pragma unroll
        for (int n = 0; n < 2; ++n) {
            int row0 = brow + wr * 64 + m * 16 + lg * 4;
            int col  = bcol + wc * 32 + n * 16 + l15;
#pragma unroll
            for (int j = 0; j < 4; ++j) {
                float v = acc[m][n][j];
                if (F32OUT)
                    ((float*)Cv)[(size_t)(row0 + j) * N + col] = v;
                else
                    ((ushort*)Cv)[(size_t)(row0 + j) * N + col] = f2b(v);
            }
        }
}

// ---------------- fused QKV projection: r4 structure + T4 counted-vmcnt 3-ring --------
// EXPERIMENT (isolated): BK=32, 128x128, 8 waves, 576 blocks — all unchanged — but LDS
// is a 3-deep ring (48 KiB; still fully resident: 576 < 768 at the 3/CU LDS cap).
// Per step t: B1 (orders compute(t-1) reads vs overwrite of buf[(t+2)%3]=buf[(t-1)%3])
// -> stage(t+2) -> vmcnt(4) (own stage(t) landed; all waves pass this before B2, so
// after B2 buf[t%3] is globally complete) -> B2 -> sched_barrier(0) -> compute(t).
// Loads for t+1/t+2 (4 per thread) stay in flight across B2 — the T4 mechanism at
// unchanged occupancy. Tail peeled: vmcnt(2), then vmcnt(0).
__global__ __launch_bounds__(512) void gemm_qkv(const ushort* __restrict__ A,
                                                const ushort* __restrict__ B,
                                                ushort* __restrict__ Cq,
                                                ushort* __restrict__ Ckv,
                                                ushort* __restrict__ Vt,
                                                int M, int K)
{
    __shared__ ushort As[3][128 * 32];
    __shared__ ushort Bs[3][128 * 32];
    const int tid  = threadIdx.x;
    const int lane = tid & 63;
    const int wid  = tid >> 6;
    const int l15  = lane & 15;
    const int lg   = lane >> 4;
    const int nwg8 = gridDim.x >> 3;
    const int kblk = blockIdx.x;
    const int swz  = (kblk & 7) * nwg8 + (kblk >> 3);
    const int brow = (swz / 18) * 128;
    const int bcol = (swz % 18) * 128;
    const int wr = wid >> 2, wc = wid & 3;

    f32x4 acc[4][2] = {};

    auto stage = [&](int bi, int k0) {
        const ushort* Ap = A + (size_t)brow * K + k0;
        const ushort* Bp = B + (size_t)bcol * K + k0;
        const int r   = tid >> 2;
        const int sgc = (tid & 3) ^ ((r >> 1) & 3);
        __builtin_amdgcn_global_load_lds(
            (const AS1 void*)(Ap + (size_t)r * K + sgc * 8),
            (AS3 void*)(&As[bi][wid * 512]), 16, 0, 0);
        __builtin_amdgcn_global_load_lds(
            (const AS1 void*)(Bp + (size_t)r * K + sgc * 8),
            (AS3 void*)(&Bs[bi][wid * 512]), 16, 0, 0);
    };

    auto compute = [&](int cur) {
        bf16x8 af[4], bfr[2];
#pragma unroll
        for (int m = 0; m < 4; ++m) {
            int row = wr * 64 + m * 16 + l15;
            int slot = lg ^ ((row >> 1) & 3);
            af[m] = *(const bf16x8*)(&As[cur][row * 32 + slot * 8]);
        }
#pragma unroll
        for (int n = 0; n < 2; ++n) {
            int row = wc * 32 + n * 16 + l15;
            int slot = lg ^ ((row >> 1) & 3);
            bfr[n] = *(const bf16x8*)(&Bs[cur][row * 32 + slot * 8]);
        }
#pragma unroll
        for (int m = 0; m < 4; ++m)
#pragma unroll
            for (int n = 0; n < 2; ++n)
                acc[m][n] = __builtin_amdgcn_mfma_f32_16x16x32_bf16(af[m], bfr[n], acc[m][n], 0, 0, 0);
    };

    const int NT = K >> 5;   // 64
    stage(0, 0);
    stage(1, 32);

#pragma unroll 1
    for (int t = 0; t < NT - 2; ++t) {
        __builtin_amdgcn_s_barrier();                       // B1
        stage((t + 2) % 3, (t + 2) * 32);
        asm volatile("s_waitcnt vmcnt(4)" ::: "memory");    // own stage(t) landed
        __builtin_amdgcn_s_barrier();                       // B2: buf[t%3] globally ready
        __builtin_amdgcn_sched_barrier(0);
        compute(t % 3);
    }
    // t = NT-2 (62): nothing to stage; only stage(NT-1) = 2 loads outstanding
    __builtin_amdgcn_s_barrier();
    asm volatile("s_waitcnt vmcnt(2)" ::: "memory");
    __builtin_amdgcn_s_barrier();
    __builtin_amdgcn_sched_barrier(0);
    compute((NT - 2) % 3);
    // t = NT-1 (63)
    __builtin_amdgcn_s_barrier();
    asm volatile("s_waitcnt vmcnt(0)" ::: "memory");
    __builtin_amdgcn_s_barrier();
    __builtin_amdgcn_sched_barrier(0);
    compute((NT - 1) % 3);

    const bool toK = (bcol == 2048);
    const bool toV = (bcol == 2176);
#pragma unroll
    for (int m = 0; m < 4; ++m)
#pragma unroll
        for (int n = 0; n < 2; ++n) {
            int row0 = brow + wr * 64 + m * 16 + lg * 4;
            int col  = bcol + wc * 32 + n * 16 + l15;
#pragma unroll
            for (int j = 0; j < 4; ++j) {
                float v = acc[m][n][j];
                int row = row0 + j;
                if (toV) {
                    int d = col - 2176;
                    int bb = row >> 11, s = row & 2047;
                    Vt[((size_t)(bb * 128 + d)) * 2048 + s] = f2b(v);
                } else if (toK) {
                    Ckv[(size_t)row * 256 + (col - 2048)] = f2b(v);
                } else {
                    Cq[(size_t)row * 2048 + col] = f2b(v);
                }
            }
        }
}

// ---------------- MQA causal flash attention (r19/r20 attn12) --------------------------
__global__ __launch_bounds__(256, 2) void mqa_attn12(const ushort* __restrict__ Q,
                                                     const ushort* __restrict__ KV,
                                                     const ushort* __restrict__ Vt,
                                                     ushort* __restrict__ O)
{
    const int tid = threadIdx.x, lane = tid & 63, wid = tid >> 6;
    const int c31 = lane & 31, H = lane >> 5;
    const int bid = blockIdx.x;
    const int a  = bid & 31;
    const int hp = (bid >> 5) & 7;
    const int b  = bid >> 8;
    const int h  = hp * 2 + (wid >> 1);
    const int p  = wid & 1;

    __shared__ __align__(16) ushort SMEM[32768];  // 64 KB

    const ushort* KVb = KV + (size_t)b * 2048 * 256;
    const ushort* Vtb = Vt + (size_t)b * 128 * 2048;
    const float C2 = 0.12751763f;       // (1/sqrt(128)) * log2(e)
    const float mC = 32.0f * C2;        // fixed max (raw units)

    auto stageK = [&](int buf, int par, int t) {
        ushort* dst = SMEM + (buf * 2 + par) * 4096;
        const int kvb = t * 32;
#pragma unroll
        for (int i = 0; i < 8; ++i) {
            int G = i * 64 + lane;
            int r = G >> 4, gc = G & 15;
            int sgc = gc ^ (r & 15);
            __builtin_amdgcn_global_load_lds(
                (const AS1 void*)(KVb + (size_t)(kvb + r) * 256 + sgc * 8),
                (AS3 void*)(dst + i * 512), 16, 0, 0);
        }
    };
    auto stageV = [&](int buf, int par, int t) {
        ushort* dst = SMEM + 16384 + (buf * 2 + par) * 4096;
        const int kvb = t * 32;
#pragma unroll
        for (int i = 0; i < 8; ++i) {
            int G = i * 64 + lane;
            int g = G >> 3, s = G & 7;
            int u = s ^ (g & 7);
            int r = 2 * g + (u & 1);
            int cc = u >> 1;
            __builtin_amdgcn_global_load_lds(
                (const AS1 void*)(Vtb + (size_t)r * 2048 + kvb + cc * 8),
                (AS3 void*)(dst + G * 8), 16, 0, 0);
        }
    };

#pragma unroll 1
    for (int phase = 0; phase < 2; ++phase) {
        const int tile  = phase ? (63 - a) : a;
        const int qtile = tile * 32;
        const int U = tile + 1;
        const int S = (U + 1) >> 1;
        const size_t qrow = (size_t)(b * 2048 + qtile + c31);

        bf16x8 qf[8];
#pragma unroll
        for (int dk = 0; dk < 8; ++dk)
            qf[dk] = *(const bf16x8*)(Q + qrow * 2048 + h * 128 + dk * 16 + H * 8);

        float l_run = 0.f;
        f32x16 of[4];
#pragma unroll
        for (int dt = 0; dt < 4; ++dt)
#pragma unroll
            for (int r = 0; r < 16; ++r) of[dt][r] = 0.f;

        {
            int t = p;
            if (t < U) { if (wid < 2) stageK(0, p, t); else stageV(0, p, t); }
        }
        __syncthreads();

#pragma unroll 1
        for (int s = 0; s < S; ++s) {
            if (s + 1 < S) {
                int tn = 2 * (s + 1) + p;
                if (tn < U) { if (wid < 2) stageK((s + 1) & 1, p, tn); else stageV((s + 1) & 1, p, tn); }
            }
            const int t = 2 * s + p;
            if (t < U) {
                const ushort* Kb = SMEM + ((s & 1) * 2 + p) * 4096;
                const ushort* Vb = SMEM + 16384 + ((s & 1) * 2 + p) * 4096;
                const bool maskt = (t == tile);

                f32x16 sg = {0,0,0,0,0,0,0,0,0,0,0,0,0,0,0,0};
                __builtin_amdgcn_s_setprio(1);
#pragma unroll
                for (int dk = 0; dk < 8; ++dk) {
                    bf16x8 kf = *(const bf16x8*)(Kb + c31 * 128 + ((dk * 16 + H * 8) ^ ((c31 & 15) << 3)));
                    sg = __builtin_amdgcn_mfma_f32_32x32x16_bf16(kf, qf[dk], sg, 0, 0, 0);
                }
                __builtin_amdgcn_s_setprio(0);

                float e[16];
#pragma unroll
                for (int r = 0; r < 16; ++r) {
                    float v = sg[r];
                    if (maskt) {
                        int crow = (r & 3) + 8 * (r >> 2) + 4 * H;
                        if (crow > c31) v = -1e30f;
                    }
                    e[r] = __builtin_amdgcn_exp2f(__builtin_fmaf(v, C2, -mC));
                }
                float rsum = 0.f;
#pragma unroll
                for (int r = 0; r < 16; ++r) rsum += e[r];
                rsum += __shfl_xor(rsum, 32);
                l_run += rsum;

                unsigned pk[8];
#pragma unroll
                for (int i = 0; i < 8; ++i)
                    asm("v_cvt_pk_bf16_f32 %0, %1, %2" : "=v"(pk[i]) : "v"(e[2 * i]), "v"(e[2 * i + 1]));
                asm("v_permlane32_swap_b32 %0, %1" : "+v"(pk[0]), "+v"(pk[2]));
                asm("v_permlane32_swap_b32 %0, %1" : "+v"(pk[1]), "+v"(pk[3]));
                asm("v_permlane32_swap_b32 %0, %1" : "+v"(pk[4]), "+v"(pk[6]));
                asm("v_permlane32_swap_b32 %0, %1" : "+v"(pk[5]), "+v"(pk[7]));
                union { unsigned u[4]; bf16x8 v; } P0, P1;
                P0.u[0] = pk[0]; P0.u[1] = pk[1]; P0.u[2] = pk[2]; P0.u[3] = pk[3];
                P1.u[0] = pk[4]; P1.u[1] = pk[5]; P1.u[2] = pk[6]; P1.u[3] = pk[7];

                __builtin_amdgcn_s_setprio(1);
#pragma unroll
                for (int dt = 0; dt < 4; ++dt) {
                    int g  = dt * 16 + (c31 >> 1);
                    int sw = g & 7;
                    int b0 = c31 & 1;
                    int s0 = (2 * H + b0) ^ sw;
                    int s1 = (4 + 2 * H + b0) ^ sw;
                    bf16x8 v0 = *(const bf16x8*)(Vb + (g * 8 + s0) * 8);
                    bf16x8 v1 = *(const bf16x8*)(Vb + (g * 8 + s1) * 8);
                    of[dt] = __builtin_amdgcn_mfma_f32_32x32x16_bf16(v0, P0.v, of[dt], 0, 0, 0);
                    of[dt] = __builtin_amdgcn_mfma_f32_32x32x16_bf16(v1, P1.v, of[dt], 0, 0, 0);
                }
                __builtin_amdgcn_s_setprio(0);
            }
            __syncthreads();
        }

        // ---- merge kv-parities (fixed m -> l's simply add) ----
        float* mlb = (float*)SMEM;
        if (H == 0) mlb[wid * 32 + c31] = l_run;
        __syncthreads();
        {
            float lo = mlb[(wid ^ 1) * 32 + c31];
            float inv = 1.0f / (l_run + lo);
            float* ob = (float*)(SMEM + 512) + (wid >> 1) * 4096;
            if (p == 1) {
#pragma unroll
                for (int dt = 0; dt < 4; ++dt)
#pragma unroll
                    for (int rq = 0; rq < 4; ++rq) {
                        f32x4 w;
#pragma unroll
                        for (int j = 0; j < 4; ++j) w[j] = of[dt][rq * 4 + j];
                        *(f32x4*)(ob + ((dt * 4 + rq) * 64 + lane) * 4) = w;
                    }
            }
            __syncthreads();
            if (p == 0) {
                ushort* Orow = O + qrow * 2048 + h * 128;
#pragma unroll
                for (int dt = 0; dt < 4; ++dt)
#pragma unroll
                    for (int rq = 0; rq < 4; ++rq) {
                        f32x4 r4 = *(const f32x4*)(ob + ((dt * 4 + rq) * 64 + lane) * 4);
                        u16x4 o4;
#pragma unroll
                        for (int j = 0; j < 4; ++j)
                            o4[j] = f2b((of[dt][rq * 4 + j] + r4[j]) * inv);
                        int d0 = dt * 32 + rq * 8 + 4 * H;
                        *(u16x4*)(Orow + d0) = o4;
                    }
            }
        }
        __syncthreads();
    }
}

extern "C" void kernel_launch(void* const* d_in, const int* in_sizes, int n_in,
                              void* d_out, int out_size, void* d_ws, size_t ws_size,
                              hipStream_t stream) {
    const float* x   = (const float*)d_in[0];
    const float* Wq  = (const float*)d_in[1];
    const float* Wkv = (const float*)d_in[2];
    const float* Wo  = (const float*)d_in[3];

    char* ws = (char*)d_ws;
    ushort* xb    = (ushort*)(ws);             // [4096][2048] bf16 (16 MB); reused as aob after gemm_qkv
    ushort* wqkvb = (ushort*)(ws + 16777216);  // [2304][2048] (18 MB)
    ushort* wob   = (ushort*)(ws + 35651584);  // [2048][2048] (8 MB)
    ushort* qb    = (ushort*)(ws + 44040192);  // [4096][2048] (16 MB)
    ushort* kvb   = (ushort*)(ws + 60817408);  // [4096][256]  (2 MB, K half used)
    ushort* vtb   = (ushort*)(ws + 62914560);  // [2][128][2048] (1 MB)
    ushort* aob   = xb;                        // attn output aliases xb

    cvt_all<<<2048, 256, 0, stream>>>(x, Wq, Wkv, Wo, xb, wqkvb, wob);

    gemm_qkv<<<576, 512, 0, stream>>>(xb, wqkvb, qb, kvb, vtb, 4096, 2048);
    mqa_attn12<<<512, 256, 0, stream>>>(qb, kvb, vtb, aob);
    gemm_bt<true><<<512, 512, 0, stream>>>(aob, wob, d_out, 4096, 2048, 2048);
}

// Round 12
// 165.465 us; speedup vs baseline: 1.0120x; 1.0120x over previous
//
#include <hip/hip_runtime.h>
#include <hip/hip_bf16.h>

typedef __attribute__((ext_vector_type(8))) short bf16x8;
typedef __attribute__((ext_vector_type(4))) float f32x4;
typedef __attribute__((ext_vector_type(16))) float f32x16;
typedef __attribute__((ext_vector_type(4))) ushort u16x4;

#define AS1 __attribute__((address_space(1)))
#define AS3 __attribute__((address_space(3)))

static __device__ __forceinline__ ushort f2b(float f) {
    union { float f; unsigned u; } v;
    v.f = f;
    unsigned r = v.u + 0x7FFF + ((v.u >> 16) & 1);
    return (ushort)(r >> 16);
}

// ---------------- fused f32 -> bf16 conversion (x, Wq, Wkv, Wo) ----------------
__global__ __launch_bounds__(256) void cvt_all(const float* __restrict__ x,
                                               const float* __restrict__ Wq,
                                               const float* __restrict__ Wkv,
                                               const float* __restrict__ Wo,
                                               ushort* __restrict__ xb,
                                               ushort* __restrict__ wqkvb,
                                               ushort* __restrict__ wob)
{
    int i = blockIdx.x * blockDim.x + threadIdx.x;
    const int stride = gridDim.x * blockDim.x;
    for (; i < 4325376; i += stride) {
        const float4* src; ushort4* dst; int j;
        if (i < 2097152)      { src = (const float4*)x;   dst = (ushort4*)xb;              j = i; }
        else if (i < 3145728) { src = (const float4*)Wq;  dst = (ushort4*)wqkvb;           j = i - 2097152; }
        else if (i < 3276800) { src = (const float4*)Wkv; dst = (ushort4*)wqkvb + 1048576; j = i - 3145728; }
        else                  { src = (const float4*)Wo;  dst = (ushort4*)wob;             j = i - 3276800; }
        float4 v = src[j];
        ushort4 o; o.x = f2b(v.x); o.y = f2b(v.y); o.z = f2b(v.z); o.w = f2b(v.w);
        dst[j] = o;
    }
}

// ---------------- bf16 GEMM: C = A * B^T (session best: BK=64 dbuf + 8 waves) ---------
// 128x128 tile, BK=64, 8 waves (2M x 4N), per-wave 64x32 (4x2 frags, 16 MFMA/K-step).
// 64 KiB LDS, 512 blocks = exactly 2.0 blocks/CU. Measured 48.5 us (708 TF, r10).
// Frozen: BK (r3/r6), waves (r0/r4), MFMA shape (r7), blocks/CU (r5/r6), counted
// vmcnt (r11) all tested; this is the composed best.
template<bool F32OUT>
__global__ __launch_bounds__(512) void gemm_bt(const ushort* __restrict__ A,
                                               const ushort* __restrict__ B,
                                               void* __restrict__ Cv,
                                               int M, int N, int K)
{
    __shared__ ushort As[2][128 * 64];
    __shared__ ushort Bs[2][128 * 64];
    const int tid  = threadIdx.x;
    const int lane = tid & 63;
    const int wid  = tid >> 6;
    const int l15  = lane & 15;
    const int lg   = lane >> 4;
    const int nwg8 = gridDim.x >> 3;
    const int kblk = blockIdx.x;
    const int swz  = (kblk & 7) * nwg8 + (kblk >> 3);
    const int nx   = N >> 7;
    const int brow = (swz / nx) * 128;
    const int bcol = (swz % nx) * 128;
    const int wr = wid >> 2, wc = wid & 3;

    f32x4 acc[4][2] = {};

    auto stage = [&](int bi, int k0) {
        const ushort* Ap = A + (size_t)brow * K + k0;
        const ushort* Bp = B + (size_t)bcol * K + k0;
#pragma unroll
        for (int j = 0; j < 2; ++j) {
            const int G = j * 512 + tid;
            const int r = G >> 3;
            const int s = (G & 7) ^ (r & 7);
            const int dc = j * 4096 + (wid << 9);
            __builtin_amdgcn_global_load_lds(
                (const AS1 void*)(Ap + (size_t)r * K + s * 8),
                (AS3 void*)(&As[bi][dc]), 16, 0, 0);
            __builtin_amdgcn_global_load_lds(
                (const AS1 void*)(Bp + (size_t)r * K + s * 8),
                (AS3 void*)(&Bs[bi][dc]), 16, 0, 0);
        }
    };

    stage(0, 0);
    __syncthreads();
    int cur = 0;

    for (int k0 = 0; k0 < K; k0 += 64) {
        if (k0 + 64 < K) stage(cur ^ 1, k0 + 64);

        bf16x8 af[4][2], bfr[2][2];
#pragma unroll
        for (int m = 0; m < 4; ++m) {
            int row = wr * 64 + m * 16 + l15;
#pragma unroll
            for (int kh = 0; kh < 2; ++kh) {
                int sl = (kh * 4 + lg) ^ (row & 7);
                af[m][kh] = *(const bf16x8*)(&As[cur][row * 64 + sl * 8]);
            }
        }
#pragma unroll
        for (int n = 0; n < 2; ++n) {
            int row = wc * 32 + n * 16 + l15;
#pragma unroll
            for (int kh = 0; kh < 2; ++kh) {
                int sl = (kh * 4 + lg) ^ (row & 7);
                bfr[n][kh] = *(const bf16x8*)(&Bs[cur][row * 64 + sl * 8]);
            }
        }
#pragma unroll
        for (int m = 0; m < 4; ++m)
#pragma unroll
            for (int n = 0; n < 2; ++n) {
                acc[m][n] = __builtin_amdgcn_mfma_f32_16x16x32_bf16(af[m][0], bfr[n][0], acc[m][n], 0, 0, 0);
                acc[m][n] = __builtin_amdgcn_mfma_f32_16x16x32_bf16(af[m][1], bfr[n][1], acc[m][n], 0, 0, 0);
            }

        __syncthreads();
        cur ^= 1;
    }

#pragma unroll
    for (int m = 0; m < 4; ++m)
#pragma unroll
        for (int n = 0; n < 2; ++n) {
            int row0 = brow + wr * 64 + m * 16 + lg * 4;
            int col  = bcol + wc * 32 + n * 16 + l15;
#pragma unroll
            for (int j = 0; j < 4; ++j) {
                float v = acc[m][n][j];
                if (F32OUT)
                    ((float*)Cv)[(size_t)(row0 + j) * N + col] = v;
                else
                    ((ushort*)Cv)[(size_t)(row0 + j) * N + col] = f2b(v);
            }
        }
}

// ---------------- fused QKV projection (session best: 576 blocks, 8 waves, BK=32) -----
// 63.1 us (604 TF), reproduced 4x (r4/r7/r10/r11). The ~604 TF plateau is the
// 2-barrier structure's dependency-limited rate at this shape: occupancy (r4),
// blocks/CU (r5/r6), BK (r3), MFMA shape (r7), counted-vmcnt T4 (r11) all null;
// 8-phase falsified 3x at this grid scale (r1/r2/r9 — needs >=1 block/CU x 256 CUs).
__global__ __launch_bounds__(512) void gemm_qkv(const ushort* __restrict__ A,
                                                const ushort* __restrict__ B,
                                                ushort* __restrict__ Cq,
                                                ushort* __restrict__ Ckv,
                                                ushort* __restrict__ Vt,
                                                int M, int K)
{
    __shared__ ushort As[2][128 * 32];
    __shared__ ushort Bs[2][128 * 32];
    const int tid  = threadIdx.x;
    const int lane = tid & 63;
    const int wid  = tid >> 6;
    const int l15  = lane & 15;
    const int lg   = lane >> 4;
    const int nwg8 = gridDim.x >> 3;
    const int kblk = blockIdx.x;
    const int swz  = (kblk & 7) * nwg8 + (kblk >> 3);
    const int brow = (swz / 18) * 128;
    const int bcol = (swz % 18) * 128;
    const int wr = wid >> 2, wc = wid & 3;

    f32x4 acc[4][2] = {};

    auto stage = [&](int bi, int k0) {
        const ushort* Ap = A + (size_t)brow * K + k0;
        const ushort* Bp = B + (size_t)bcol * K + k0;
        const int r   = tid >> 2;
        const int sgc = (tid & 3) ^ ((r >> 1) & 3);
        __builtin_amdgcn_global_load_lds(
            (const AS1 void*)(Ap + (size_t)r * K + sgc * 8),
            (AS3 void*)(&As[bi][wid * 512]), 16, 0, 0);
        __builtin_amdgcn_global_load_lds(
            (const AS1 void*)(Bp + (size_t)r * K + sgc * 8),
            (AS3 void*)(&Bs[bi][wid * 512]), 16, 0, 0);
    };

    stage(0, 0);
    __syncthreads();
    int cur = 0;

    for (int k0 = 0; k0 < K; k0 += 32) {
        if (k0 + 32 < K) stage(cur ^ 1, k0 + 32);

        bf16x8 af[4], bfr[2];
#pragma unroll
        for (int m = 0; m < 4; ++m) {
            int row = wr * 64 + m * 16 + l15;
            int slot = lg ^ ((row >> 1) & 3);
            af[m] = *(const bf16x8*)(&As[cur][row * 32 + slot * 8]);
        }
#pragma unroll
        for (int n = 0; n < 2; ++n) {
            int row = wc * 32 + n * 16 + l15;
            int slot = lg ^ ((row >> 1) & 3);
            bfr[n] = *(const bf16x8*)(&Bs[cur][row * 32 + slot * 8]);
        }
#pragma unroll
        for (int m = 0; m < 4; ++m)
#pragma unroll
            for (int n = 0; n < 2; ++n)
                acc[m][n] = __builtin_amdgcn_mfma_f32_16x16x32_bf16(af[m], bfr[n], acc[m][n], 0, 0, 0);

        __syncthreads();
        cur ^= 1;
    }

    const bool toK = (bcol == 2048);
    const bool toV = (bcol == 2176);
#pragma unroll
    for (int m = 0; m < 4; ++m)
#pragma unroll
        for (int n = 0; n < 2; ++n) {
            int row0 = brow + wr * 64 + m * 16 + lg * 4;
            int col  = bcol + wc * 32 + n * 16 + l15;
#pragma unroll
            for (int j = 0; j < 4; ++j) {
                float v = acc[m][n][j];
                int row = row0 + j;
                if (toV) {
                    int d = col - 2176;
                    int bb = row >> 11, s = row & 2047;
                    Vt[((size_t)(bb * 128 + d)) * 2048 + s] = f2b(v);
                } else if (toK) {
                    Ckv[(size_t)row * 256 + (col - 2048)] = f2b(v);
                } else {
                    Cq[(size_t)row * 2048 + col] = f2b(v);
                }
            }
        }
}

// ---------------- MQA causal flash attention (r19/r20 attn12, ~37 us, ~930 TF) --------
__global__ __launch_bounds__(256, 2) void mqa_attn12(const ushort* __restrict__ Q,
                                                     const ushort* __restrict__ KV,
                                                     const ushort* __restrict__ Vt,
                                                     ushort* __restrict__ O)
{
    const int tid = threadIdx.x, lane = tid & 63, wid = tid >> 6;
    const int c31 = lane & 31, H = lane >> 5;
    const int bid = blockIdx.x;
    const int a  = bid & 31;
    const int hp = (bid >> 5) & 7;
    const int b  = bid >> 8;
    const int h  = hp * 2 + (wid >> 1);
    const int p  = wid & 1;

    __shared__ __align__(16) ushort SMEM[32768];  // 64 KB

    const ushort* KVb = KV + (size_t)b * 2048 * 256;
    const ushort* Vtb = Vt + (size_t)b * 128 * 2048;
    const float C2 = 0.12751763f;       // (1/sqrt(128)) * log2(e)
    const float mC = 32.0f * C2;        // fixed max (raw units)

    auto stageK = [&](int buf, int par, int t) {
        ushort* dst = SMEM + (buf * 2 + par) * 4096;
        const int kvb = t * 32;
#pragma unroll
        for (int i = 0; i < 8; ++i) {
            int G = i * 64 + lane;
            int r = G >> 4, gc = G & 15;
            int sgc = gc ^ (r & 15);
            __builtin_amdgcn_global_load_lds(
                (const AS1 void*)(KVb + (size_t)(kvb + r) * 256 + sgc * 8),
                (AS3 void*)(dst + i * 512), 16, 0, 0);
        }
    };
    auto stageV = [&](int buf, int par, int t) {
        ushort* dst = SMEM + 16384 + (buf * 2 + par) * 4096;
        const int kvb = t * 32;
#pragma unroll
        for (int i = 0; i < 8; ++i) {
            int G = i * 64 + lane;
            int g = G >> 3, s = G & 7;
            int u = s ^ (g & 7);
            int r = 2 * g + (u & 1);
            int cc = u >> 1;
            __builtin_amdgcn_global_load_lds(
                (const AS1 void*)(Vtb + (size_t)r * 2048 + kvb + cc * 8),
                (AS3 void*)(dst + G * 8), 16, 0, 0);
        }
    };

#pragma unroll 1
    for (int phase = 0; phase < 2; ++phase) {
        const int tile  = phase ? (63 - a) : a;
        const int qtile = tile * 32;
        const int U = tile + 1;
        const int S = (U + 1) >> 1;
        const size_t qrow = (size_t)(b * 2048 + qtile + c31);

        bf16x8 qf[8];
#pragma unroll
        for (int dk = 0; dk < 8; ++dk)
            qf[dk] = *(const bf16x8*)(Q + qrow * 2048 + h * 128 + dk * 16 + H * 8);

        float l_run = 0.f;
        f32x16 of[4];
#pragma unroll
        for (int dt = 0; dt < 4; ++dt)
#pragma unroll
            for (int r = 0; r < 16; ++r) of[dt][r] = 0.f;

        {
            int t = p;
            if (t < U) { if (wid < 2) stageK(0, p, t); else stageV(0, p, t); }
        }
        __syncthreads();

#pragma unroll 1
        for (int s = 0; s < S; ++s) {
            if (s + 1 < S) {
                int tn = 2 * (s + 1) + p;
                if (tn < U) { if (wid < 2) stageK((s + 1) & 1, p, tn); else stageV((s + 1) & 1, p, tn); }
            }
            const int t = 2 * s + p;
            if (t < U) {
                const ushort* Kb = SMEM + ((s & 1) * 2 + p) * 4096;
                const ushort* Vb = SMEM + 16384 + ((s & 1) * 2 + p) * 4096;
                const bool maskt = (t == tile);

                f32x16 sg = {0,0,0,0,0,0,0,0,0,0,0,0,0,0,0,0};
                __builtin_amdgcn_s_setprio(1);
#pragma unroll
                for (int dk = 0; dk < 8; ++dk) {
                    bf16x8 kf = *(const bf16x8*)(Kb + c31 * 128 + ((dk * 16 + H * 8) ^ ((c31 & 15) << 3)));
                    sg = __builtin_amdgcn_mfma_f32_32x32x16_bf16(kf, qf[dk], sg, 0, 0, 0);
                }
                __builtin_amdgcn_s_setprio(0);

                float e[16];
#pragma unroll
                for (int r = 0; r < 16; ++r) {
                    float v = sg[r];
                    if (maskt) {
                        int crow = (r & 3) + 8 * (r >> 2) + 4 * H;
                        if (crow > c31) v = -1e30f;
                    }
                    e[r] = __builtin_amdgcn_exp2f(__builtin_fmaf(v, C2, -mC));
                }
                float rsum = 0.f;
#pragma unroll
                for (int r = 0; r < 16; ++r) rsum += e[r];
                rsum += __shfl_xor(rsum, 32);
                l_run += rsum;

                unsigned pk[8];
#pragma unroll
                for (int i = 0; i < 8; ++i)
                    asm("v_cvt_pk_bf16_f32 %0, %1, %2" : "=v"(pk[i]) : "v"(e[2 * i]), "v"(e[2 * i + 1]));
                asm("v_permlane32_swap_b32 %0, %1" : "+v"(pk[0]), "+v"(pk[2]));
                asm("v_permlane32_swap_b32 %0, %1" : "+v"(pk[1]), "+v"(pk[3]));
                asm("v_permlane32_swap_b32 %0, %1" : "+v"(pk[4]), "+v"(pk[6]));
                asm("v_permlane32_swap_b32 %0, %1" : "+v"(pk[5]), "+v"(pk[7]));
                union { unsigned u[4]; bf16x8 v; } P0, P1;
                P0.u[0] = pk[0]; P0.u[1] = pk[1]; P0.u[2] = pk[2]; P0.u[3] = pk[3];
                P1.u[0] = pk[4]; P1.u[1] = pk[5]; P1.u[2] = pk[6]; P1.u[3] = pk[7];

                __builtin_amdgcn_s_setprio(1);
#pragma unroll
                for (int dt = 0; dt < 4; ++dt) {
                    int g  = dt * 16 + (c31 >> 1);
                    int sw = g & 7;
                    int b0 = c31 & 1;
                    int s0 = (2 * H + b0) ^ sw;
                    int s1 = (4 + 2 * H + b0) ^ sw;
                    bf16x8 v0 = *(const bf16x8*)(Vb + (g * 8 + s0) * 8);
                    bf16x8 v1 = *(const bf16x8*)(Vb + (g * 8 + s1) * 8);
                    of[dt] = __builtin_amdgcn_mfma_f32_32x32x16_bf16(v0, P0.v, of[dt], 0, 0, 0);
                    of[dt] = __builtin_amdgcn_mfma_f32_32x32x16_bf16(v1, P1.v, of[dt], 0, 0, 0);
                }
                __builtin_amdgcn_s_setprio(0);
            }
            __syncthreads();
        }

        // ---- merge kv-parities (fixed m -> l's simply add) ----
        float* mlb = (float*)SMEM;
        if (H == 0) mlb[wid * 32 + c31] = l_run;
        __syncthreads();
        {
            float lo = mlb[(wid ^ 1) * 32 + c31];
            float inv = 1.0f / (l_run + lo);
            float* ob = (float*)(SMEM + 512) + (wid >> 1) * 4096;
            if (p == 1) {
#pragma unroll
                for (int dt = 0; dt < 4; ++dt)
#pragma unroll
                    for (int rq = 0; rq < 4; ++rq) {
                        f32x4 w;
#pragma unroll
                        for (int j = 0; j < 4; ++j) w[j] = of[dt][rq * 4 + j];
                        *(f32x4*)(ob + ((dt * 4 + rq) * 64 + lane) * 4) = w;
                    }
            }
            __syncthreads();
            if (p == 0) {
                ushort* Orow = O + qrow * 2048 + h * 128;
#pragma unroll
                for (int dt = 0; dt < 4; ++dt)
#pragma unroll
                    for (int rq = 0; rq < 4; ++rq) {
                        f32x4 r4 = *(const f32x4*)(ob + ((dt * 4 + rq) * 64 + lane) * 4);
                        u16x4 o4;
#pragma unroll
                        for (int j = 0; j < 4; ++j)
                            o4[j] = f2b((of[dt][rq * 4 + j] + r4[j]) * inv);
                        int d0 = dt * 32 + rq * 8 + 4 * H;
                        *(u16x4*)(Orow + d0) = o4;
                    }
            }
        }
        __syncthreads();
    }
}

extern "C" void kernel_launch(void* const* d_in, const int* in_sizes, int n_in,
                              void* d_out, int out_size, void* d_ws, size_t ws_size,
                              hipStream_t stream) {
    const float* x   = (const float*)d_in[0];
    const float* Wq  = (const float*)d_in[1];
    const float* Wkv = (const float*)d_in[2];
    const float* Wo  = (const float*)d_in[3];

    char* ws = (char*)d_ws;
    ushort* xb    = (ushort*)(ws);             // [4096][2048] bf16 (16 MB); reused as aob after gemm_qkv
    ushort* wqkvb = (ushort*)(ws + 16777216);  // [2304][2048] (18 MB)
    ushort* wob   = (ushort*)(ws + 35651584);  // [2048][2048] (8 MB)
    ushort* qb    = (ushort*)(ws + 44040192);  // [4096][2048] (16 MB)
    ushort* kvb   = (ushort*)(ws + 60817408);  // [4096][256]  (2 MB, K half used)
    ushort* vtb   = (ushort*)(ws + 62914560);  // [2][128][2048] (1 MB)
    ushort* aob   = xb;                        // attn output aliases xb

    cvt_all<<<2048, 256, 0, stream>>>(x, Wq, Wkv, Wo, xb, wqkvb, wob);

    gemm_qkv<<<576, 512, 0, stream>>>(xb, wqkvb, qb, kvb, vtb, 4096, 2048);
    mqa_attn12<<<512, 256, 0, stream>>>(qb, kvb, vtb, aob);
    gemm_bt<true><<<512, 512, 0, stream>>>(aob, wob, d_out, 4096, 2048, 2048);
}